// Round 7
// baseline (590.508 us; speedup 1.0000x reference)
//
#include <hip/hip_runtime.h>

#define B_DIM 64
#define S_DIM 784
#define T_DIM 500
#define N_DIM 1024
#define TP    522
#define KS    21
#define THETA 80
#define NCHUNK 8
#define CH    66
#define LISTCAP 128
#define SW64  13        // ceil(784/64) u64 words per timestep bitmap
#define BMSTRIDE 16     // padded row stride (u64 words) -> 128 B rows

// ---- K1: wt8[s][n] = w ? 8*(w-1) : 56 (shift amount; 8-bit class fields, garbage @56)
__global__ void k_prep(const int* __restrict__ w, unsigned char* __restrict__ wt8) {
  unsigned idx = blockIdx.x * 256 + threadIdx.x;
  if (idx < S_DIM * N_DIM) {
    unsigned s = idx >> 10, n = idx & 1023;
    int wv = w[n * S_DIM + s];
    wt8[idx] = wv ? (unsigned char)(8 * (wv - 1)) : (unsigned char)56;
  }
}

// ---- K2: per-(b,t) spike BITMAPS via double-ballot bit transpose (zero global atomics)
__global__ void __launch_bounds__(1024)
k_bitmap(const float* __restrict__ x, unsigned long long* __restrict__ bm) {
  __shared__ unsigned long long s_m[S_DIM];
  const int tid = threadIdx.x;
  const int wave = tid >> 6, lane = tid & 63;
  const int b = blockIdx.y;
  const int t0 = blockIdx.x * 64;
  const int t = t0 + lane;
  const bool tok = (t < T_DIM);
  const float* xb = x + (size_t)b * S_DIM * T_DIM;

  for (int s = wave; s < S_DIM; s += 16) {
    float v = tok ? xb[(size_t)s * T_DIM + t] : 0.0f;
    unsigned long long m = __ballot(v != 0.0f);
    if (lane == 0) s_m[s] = m;
  }
  __syncthreads();

  if (wave < SW64) {
    const int sbase = wave * 64;
    const unsigned long long mask_s =
        (sbase + lane < S_DIM) ? s_m[sbase + lane] : 0ull;
    unsigned long long* dst = bm + ((size_t)b * 512 + t0) * BMSTRIDE + wave;
    for (int tl = 0; tl < 64; ++tl) {
      unsigned long long wrd = __ballot((mask_s >> tl) & 1ull);
      if (lane == 0) dst[(size_t)tl * BMSTRIDE] = wrd;
    }
  }
}

// ==== chain macro: unpack packed 8-bit class counters + delta-chain ring update ====
// OFF is a compile-time literal ring offset (0 for t, 1 for t+1).
#define CHAIN(CVAL, OFF)                                                             \
  {                                                                                  \
    const unsigned clo = (unsigned)(CVAL), chi = (unsigned)((CVAL) >> 32);           \
    const int c1 = (int)(clo & 255), c2 = (int)((clo >> 8) & 255),                   \
              c3 = (int)((clo >> 16) & 255), c4 = (int)(clo >> 24);                  \
    const int c5 = (int)(chi & 255), c6 = (int)((chi >> 8) & 255),                   \
              c7 = (int)((chi >> 16) & 255);                                         \
    const int S7 = c7, S6 = S7 + c6, S5 = S6 + c5, S4 = S5 + c4,                     \
              S3 = S4 + c3, S2 = S3 + c2, S1 = S2 + c1;                              \
    const int O1 = c1, O3 = O1 + c3, O5 = O3 + c5, O7 = O5 + c7;                     \
    const int E2 = c2, E4 = E2 + c4, E6 = E4 + c6;                                   \
    const int O31 = O3 - O1, O51 = O5 - O1, O71 = O7 - O1,                           \
              O73 = O7 - O3, O75 = O7 - O5;                                          \
    const int E62 = E6 - E2, E64 = E6 - E4;                                          \
    int acc = S1;        ring[(OFF) + 1]  += acc;                                    \
    acc += S2;           ring[(OFF) + 2]  += acc;                                    \
    acc += S3 - O1;      ring[(OFF) + 3]  += acc;                                    \
    acc += S4 - E2;      ring[(OFF) + 4]  += acc;                                    \
    acc += S5 - O31;     ring[(OFF) + 5]  += acc;                                    \
    acc += S6 - E4;      ring[(OFF) + 6]  += acc;                                    \
    acc += S7 - O51;     ring[(OFF) + 7]  += acc;                                    \
    acc -= E62;          ring[(OFF) + 8]  += acc;                                    \
    acc -= O71;          ring[(OFF) + 9]  += acc;                                    \
    acc -= E62;          ring[(OFF) + 10] += acc;                                    \
    acc -= O73;          ring[(OFF) + 11] += acc;                                    \
    acc -= E62;          ring[(OFF) + 12] += acc;                                    \
    acc -= O73;          ring[(OFF) + 13] += acc;                                    \
    acc -= E64;          ring[(OFF) + 14] += acc;                                    \
    acc -= O73;          ring[(OFF) + 15] += acc;                                    \
    acc -= E64;          ring[(OFF) + 16] += acc;                                    \
    acc -= O75;          ring[(OFF) + 17] += acc;                                    \
    acc -= E64;          ring[(OFF) + 18] += acc;                                    \
    acc -= O75;          ring[(OFF) + 19] += acc;                                    \
                         ring[(OFF) + 20] += acc;                                    \
    acc -= O75;          ring[(OFF) + 21] += acc;                                    \
  }

// spike accumulation, 4 independent load streams within ONE t (R5's failure was
// fusing two t's loops; this keeps state minimal: +4 transient VGPRs vs R4)
#define SPIKES(LI, CV)                                                               \
  {                                                                                  \
    const int cnt = __builtin_amdgcn_readfirstlane(min(s_cnt[(LI)], LISTCAP));       \
    const unsigned short* lp = &s_list[(LI)][0];                                     \
    unsigned long long ca = 0, cb = 0, cc = 0, cd = 0;                               \
    int i = 0;                                                                       \
    for (; i + 3 < cnt; i += 4) {                                                    \
      const unsigned s0 = lp[i], s1 = lp[i + 1], s2 = lp[i + 2], s3 = lp[i + 3];     \
      ca += 1ull << wt8[(s0 << 10) + tid];                                           \
      cb += 1ull << wt8[(s1 << 10) + tid];                                           \
      cc += 1ull << wt8[(s2 << 10) + tid];                                           \
      cd += 1ull << wt8[(s3 << 10) + tid];                                           \
    }                                                                                \
    for (; i < cnt; ++i) ca += 1ull << wt8[((unsigned)lp[i] << 10) + tid];           \
    CV = (ca + cb) + (cc + cd);                                                      \
  }

// emit for one t: head-partial store (j<KS) or wave butterfly argmax (wave-uniform j)
#define EMIT(RV, JJ)                                                                 \
  {                                                                                  \
    if ((JJ) < KS) {                                                                 \
      hb[(size_t)(JJ) * 1024] = (unsigned short)(RV);                                \
    } else {                                                                         \
      unsigned key = ((unsigned)(RV) << 10) | invn;                                  \
      _Pragma("unroll")                                                              \
      for (int off = 32; off > 0; off >>= 1) {                                       \
        unsigned o = __shfl_xor(key, off, 64);                                       \
        key = key > o ? key : o;                                                     \
      }                                                                              \
      if ((tid & 63) == 0) atomicMax(&smax[(JJ) - KS], key);                         \
    }                                                                                \
  }

// ---- K3a (split path): halo-free chunk. 4-stream spike loop; t-loop unrolled x2
//      with static ring rotation (ring[23], one shift-by-2 per pair).
__global__ void __launch_bounds__(1024, 8)
k_mainA(const unsigned char* __restrict__ wt8,
        const unsigned long long* __restrict__ bm,
        unsigned* __restrict__ red,
        unsigned short* __restrict__ headb,
        unsigned short* __restrict__ tailb) {
  __shared__ unsigned short s_list[CH][LISTCAP];
  __shared__ int s_cnt[CH];
  __shared__ unsigned smax[CH - KS];

  const int tid = threadIdx.x;
  const int b = blockIdx.y;
  const int ck = blockIdx.x;
  const int lo = ck * CH;
  const int hi = min(TP - 1, lo + CH - 1);
  const int nt_in = min(hi, T_DIM - 1) - lo + 1;
  const int n_full = hi - lo - (KS - 1);   // t in [lo+21, hi]

  for (int i = tid; i < nt_in; i += 1024) s_cnt[i] = 0;
  for (int i = tid; i < n_full; i += 1024) smax[i] = 0u;
  __syncthreads();

  const unsigned long long* bmb = bm + ((size_t)b * 512 + lo) * BMSTRIDE;
  const int ntask = nt_in * SW64;
  for (int task = tid; task < ntask; task += 1024) {
    const int li = task / SW64;
    const int sw = task - li * SW64;
    unsigned long long w = bmb[(size_t)li * BMSTRIDE + sw];
    if (w) {
      int cc = __popcll(w);
      int pos = atomicAdd(&s_cnt[li], cc);
      const int sb = sw * 64;
      while (w) {
        int j = __builtin_ctzll(w);
        if (pos < LISTCAP) s_list[li][pos] = (unsigned short)(sb + j);
        ++pos;
        w &= (w - 1);
      }
    }
  }
  __syncthreads();

  int ring[KS + 2];                         // 23-deep: step-B chain reaches ring[22]
  #pragma unroll
  for (int i = 0; i <= KS + 1; ++i) ring[i] = 0;

  const unsigned invn = (unsigned)(1023 - tid);
  unsigned short* hb = headb + ((size_t)b * NCHUNK + ck) * (KS * 1024) + tid;

  // all chunks have an even t-count (66 or 60) and T_DIM-lo is even -> pairs aligned
  for (int t = lo; t <= hi; t += 2) {
    const int j = t - lo;

    // --- step A (t): emit then accumulate t's spikes at ring offset 0
    EMIT(ring[0], j)
    if (t < T_DIM) {
      unsigned long long cA;
      SPIKES(j, cA)
      CHAIN(cA, 0)
    }

    // --- step B (t+1): ring[1] now includes t's tau=1 contribution
    EMIT(ring[1], j + 1)
    if (t + 1 < T_DIM) {
      unsigned long long cB;
      SPIKES(j + 1, cB)
      CHAIN(cB, 1)
    }

    // one shift-by-2 per pair (21 moves + 2 zeros, vs 2x22 single shifts)
    #pragma unroll
    for (int q = 0; q <= KS - 1; ++q) ring[q] = ring[q + 2];
    ring[KS] = 0;
    ring[KS + 1] = 0;
  }

  // tail: ring[0..20] = own-spike contributions to t = hi+1 .. hi+21
  if (ck < NCHUNK - 1) {
    unsigned short* tb = tailb + ((size_t)b * NCHUNK + ck) * (KS * 1024) + tid;
    #pragma unroll
    for (int j2 = 0; j2 < KS; ++j2) tb[(size_t)j2 * 1024] = (unsigned short)ring[j2];
  }

  __syncthreads();
  for (int i = tid; i < n_full; i += 1024)
    red[(unsigned)b * TP + (unsigned)(lo + KS + i)] = smax[i];
}

// ---- K3b (split path): head fixup. full(lo+j) = head_partial + prev_tail; argmax.
__global__ void __launch_bounds__(1024)
k_fix(const unsigned short* __restrict__ headb,
      const unsigned short* __restrict__ tailb,
      unsigned* __restrict__ red) {
  __shared__ unsigned smax[KS];
  const int tid = threadIdx.x;
  const int b = blockIdx.y, ck = blockIdx.x;
  const int lo = ck * CH;
  if (tid < KS) smax[tid] = 0u;
  __syncthreads();
  const size_t base = ((size_t)b * NCHUNK + ck) * (KS * 1024) + tid;
  const unsigned invn = (unsigned)(1023 - tid);
  for (int j = 0; j < KS; ++j) {
    int v = headb[base + (size_t)j * 1024];
    if (ck > 0) v += tailb[base - (size_t)KS * 1024 + (size_t)j * 1024];
    unsigned key = ((unsigned)v << 10) | invn;
    #pragma unroll
    for (int off = 32; off > 0; off >>= 1) {
      unsigned o = __shfl_xor(key, off, 64);
      key = key > o ? key : o;
    }
    if ((tid & 63) == 0) atomicMax(&smax[j], key);
  }
  __syncthreads();
  if (tid < KS) red[(unsigned)b * TP + (unsigned)(lo + tid)] = smax[tid];
}

// ---- K3 (fallback path, ws_size too small): halo kernel, single-t body
__global__ void __launch_bounds__(1024, 8)
k_mainH(const unsigned char* __restrict__ wt8,
        const unsigned long long* __restrict__ bm,
        unsigned* __restrict__ red) {
  __shared__ unsigned short s_list[87][LISTCAP];
  __shared__ int s_cnt[87];
  __shared__ unsigned smax[CH];

  const int tid = threadIdx.x;
  const int b = blockIdx.y;
  const int lo = blockIdx.x * CH;
  const int hi = min(TP - 1, lo + CH - 1);
  const int t0 = max(0, lo - KS);
  const int n_emit = hi - lo + 1;
  const int nt_in = min(hi, T_DIM - 1) - t0 + 1;

  for (int i = tid; i < nt_in; i += 1024) s_cnt[i] = 0;
  for (int i = tid; i < n_emit; i += 1024) smax[i] = 0u;
  __syncthreads();

  const unsigned long long* bmb = bm + ((size_t)b * 512 + t0) * BMSTRIDE;
  const int ntask = nt_in * SW64;
  for (int task = tid; task < ntask; task += 1024) {
    const int li = task / SW64;
    const int sw = task - li * SW64;
    unsigned long long w = bmb[(size_t)li * BMSTRIDE + sw];
    if (w) {
      int cc = __popcll(w);
      int pos = atomicAdd(&s_cnt[li], cc);
      const int sb = sw * 64;
      while (w) {
        int j = __builtin_ctzll(w);
        if (pos < LISTCAP) s_list[li][pos] = (unsigned short)(sb + j);
        ++pos;
        w &= (w - 1);
      }
    }
  }
  __syncthreads();

  int ring[KS + 2];
  #pragma unroll
  for (int i = 0; i <= KS + 1; ++i) ring[i] = 0;

  const unsigned invn = (unsigned)(1023 - tid);

  for (int t = t0; t <= hi; ++t) {
    if (t >= lo) {
      unsigned key = ((unsigned)ring[0] << 10) | invn;
      #pragma unroll
      for (int off = 32; off > 0; off >>= 1) {
        unsigned o = __shfl_xor(key, off, 64);
        key = key > o ? key : o;
      }
      if ((tid & 63) == 0) atomicMax(&smax[t - lo], key);
    }
    if (t < T_DIM) {
      const int li = t - t0;
      unsigned long long c;
      SPIKES(li, c)
      CHAIN(c, 0)
    }
    #pragma unroll
    for (int q = 0; q < KS + 1; ++q) ring[q] = ring[q + 1];
    ring[KS + 1] = 0;
  }

  __syncthreads();
  for (int i = tid; i < n_emit; i += 1024)
    red[(unsigned)b * TP + (unsigned)(lo + i)] = smax[i];
}

// ---- K4: winner-take-all dep scan, one wave per batch row
__global__ void __launch_bounds__(256)
k_scan(const unsigned* __restrict__ red, unsigned* __restrict__ winner) {
  const int wv = (int)((blockIdx.x * 256 + threadIdx.x) >> 6);
  const int lane = threadIdx.x & 63;
  if (wv >= B_DIM) return;
  const unsigned* r = red + wv * TP;
  unsigned* wn = winner + wv * TP;
  int dep = 0;
  for (int base = 0; base < TP; base += 64) {
    const int nt = min(64, TP - base);
    unsigned key = (lane < nt) ? r[base + lane] : 0u;
    unsigned w = 0;
    for (int j = 0; j < nt; ++j) {
      unsigned kj = __shfl(key, j, 64);
      bool cond = ((int)(kj >> 10) > THETA) && (dep == 0);
      if (cond && lane == j) w = 1024u - (kj & 1023u);
      dep += cond ? 22 : 0;
      dep = max(0, dep - 1);
    }
    if (lane < nt) wn[base + lane] = w;
  }
}

// ---- K5: fused zero+scatter output fill (writes all 137 MB exactly once)
__global__ void __launch_bounds__(256)
k_fill(const unsigned* __restrict__ winner, int* __restrict__ out) {
  const int n = blockIdx.x;
  const int b = blockIdx.y;
  const unsigned* wn = winner + b * TP;
  int* o = out + ((size_t)b * N_DIM + n) * TP;
  const unsigned target = (unsigned)(n + 1);
  int2* o2 = (int2*)o;
  for (int i = threadIdx.x; i < TP / 2; i += 256) {
    int2 v;
    v.x = (wn[2 * i]     == target) ? 1 : 0;
    v.y = (wn[2 * i + 1] == target) ? 1 : 0;
    o2[i] = v;
  }
}

extern "C" void kernel_launch(void* const* d_in, const int* in_sizes, int n_in,
                              void* d_out, int out_size, void* d_ws, size_t ws_size,
                              hipStream_t stream) {
  const float* x = (const float*)d_in[0];
  const int* wgt = (const int*)d_in[1];
  int* out = (int*)d_out;

  // workspace layout
  const size_t OFF_BM   = 802816;                 // wt8: 802,816 B
  const size_t OFF_RED  = OFF_BM + 4194304;       // bm:  4,194,304 B
  const size_t OFF_WIN  = OFF_RED + 133632;       // red: 133,632 B
  const size_t OFF_HEAD = OFF_WIN + 133632;       // winner: 133,632 B
  const size_t HT_SZ    = (size_t)B_DIM * NCHUNK * KS * 1024 * 2;  // 22,020,096 B
  const size_t OFF_TAIL = OFF_HEAD + HT_SZ;
  const size_t NEED_SPLIT = OFF_TAIL + HT_SZ;     // ~49.3 MB

  unsigned char* wt8      = (unsigned char*)d_ws;
  unsigned long long* bm  = (unsigned long long*)((char*)d_ws + OFF_BM);
  unsigned* red           = (unsigned*)((char*)d_ws + OFF_RED);
  unsigned* winner        = (unsigned*)((char*)d_ws + OFF_WIN);

  k_prep<<<3136, 256, 0, stream>>>(wgt, wt8);
  k_bitmap<<<dim3(8, B_DIM), 1024, 0, stream>>>(x, bm);

  if (ws_size >= NEED_SPLIT) {
    unsigned short* headb = (unsigned short*)((char*)d_ws + OFF_HEAD);
    unsigned short* tailb = (unsigned short*)((char*)d_ws + OFF_TAIL);
    k_mainA<<<dim3(NCHUNK, B_DIM), 1024, 0, stream>>>(wt8, bm, red, headb, tailb);
    k_fix<<<dim3(NCHUNK, B_DIM), 1024, 0, stream>>>(headb, tailb, red);
  } else {
    k_mainH<<<dim3(NCHUNK, B_DIM), 1024, 0, stream>>>(wt8, bm, red);
  }

  k_scan<<<(B_DIM * 64 + 255) / 256, 256, 0, stream>>>(red, winner);
  k_fill<<<dim3(N_DIM, B_DIM), 256, 0, stream>>>(winner, out);
}

// Round 8
// 555.339 us; speedup vs baseline: 1.0633x; 1.0633x over previous
//
#include <hip/hip_runtime.h>

#define B_DIM 64
#define S_DIM 784
#define T_DIM 500
#define N_DIM 1024
#define TP    522
#define KS    21
#define THETA 80
#define NCHUNK 8
#define CH    66
#define LISTCAP 128
#define SW64  13        // ceil(784/64) u64 words per timestep bitmap
#define BMSTRIDE 16     // padded row stride (u64 words) -> 128 B rows

// ---- K1: wt8[s][n] = w ? 8*(w-1) : 56 (shift amount; 8-bit class fields, garbage @56)
__global__ void k_prep(const int* __restrict__ w, unsigned char* __restrict__ wt8) {
  unsigned idx = blockIdx.x * 256 + threadIdx.x;
  if (idx < S_DIM * N_DIM) {
    unsigned s = idx >> 10, n = idx & 1023;
    int wv = w[n * S_DIM + s];
    wt8[idx] = wv ? (unsigned char)(8 * (wv - 1)) : (unsigned char)56;
  }
}

// ---- K2: per-(b,t) spike BITMAPS via double-ballot bit transpose (zero global atomics)
__global__ void __launch_bounds__(1024)
k_bitmap(const float* __restrict__ x, unsigned long long* __restrict__ bm) {
  __shared__ unsigned long long s_m[S_DIM];
  const int tid = threadIdx.x;
  const int wave = tid >> 6, lane = tid & 63;
  const int b = blockIdx.y;
  const int t0 = blockIdx.x * 64;
  const int t = t0 + lane;
  const bool tok = (t < T_DIM);
  const float* xb = x + (size_t)b * S_DIM * T_DIM;

  for (int s = wave; s < S_DIM; s += 16) {
    float v = tok ? xb[(size_t)s * T_DIM + t] : 0.0f;
    unsigned long long m = __ballot(v != 0.0f);
    if (lane == 0) s_m[s] = m;
  }
  __syncthreads();

  if (wave < SW64) {
    const int sbase = wave * 64;
    const unsigned long long mask_s =
        (sbase + lane < S_DIM) ? s_m[sbase + lane] : 0ull;
    unsigned long long* dst = bm + ((size_t)b * 512 + t0) * BMSTRIDE + wave;
    for (int tl = 0; tl < 64; ++tl) {
      unsigned long long wrd = __ballot((mask_s >> tl) & 1ull);
      if (lane == 0) dst[(size_t)tl * BMSTRIDE] = wrd;
    }
  }
}

// ==== chain macro: unpack packed 8-bit class counters + delta-chain ring update ====
// OFF is a compile-time literal ring offset (0 for t, 1 for t+1).
#define CHAIN(CVAL, OFF)                                                             \
  {                                                                                  \
    const unsigned clo = (unsigned)(CVAL), chi = (unsigned)((CVAL) >> 32);           \
    const int c1 = (int)(clo & 255), c2 = (int)((clo >> 8) & 255),                   \
              c3 = (int)((clo >> 16) & 255), c4 = (int)(clo >> 24);                  \
    const int c5 = (int)(chi & 255), c6 = (int)((chi >> 8) & 255),                   \
              c7 = (int)((chi >> 16) & 255);                                         \
    const int S7 = c7, S6 = S7 + c6, S5 = S6 + c5, S4 = S5 + c4,                     \
              S3 = S4 + c3, S2 = S3 + c2, S1 = S2 + c1;                              \
    const int O1 = c1, O3 = O1 + c3, O5 = O3 + c5, O7 = O5 + c7;                     \
    const int E2 = c2, E4 = E2 + c4, E6 = E4 + c6;                                   \
    const int O31 = O3 - O1, O51 = O5 - O1, O71 = O7 - O1,                           \
              O73 = O7 - O3, O75 = O7 - O5;                                          \
    const int E62 = E6 - E2, E64 = E6 - E4;                                          \
    int acc = S1;        ring[(OFF) + 1]  += acc;                                    \
    acc += S2;           ring[(OFF) + 2]  += acc;                                    \
    acc += S3 - O1;      ring[(OFF) + 3]  += acc;                                    \
    acc += S4 - E2;      ring[(OFF) + 4]  += acc;                                    \
    acc += S5 - O31;     ring[(OFF) + 5]  += acc;                                    \
    acc += S6 - E4;      ring[(OFF) + 6]  += acc;                                    \
    acc += S7 - O51;     ring[(OFF) + 7]  += acc;                                    \
    acc -= E62;          ring[(OFF) + 8]  += acc;                                    \
    acc -= O71;          ring[(OFF) + 9]  += acc;                                    \
    acc -= E62;          ring[(OFF) + 10] += acc;                                    \
    acc -= O73;          ring[(OFF) + 11] += acc;                                    \
    acc -= E62;          ring[(OFF) + 12] += acc;                                    \
    acc -= O73;          ring[(OFF) + 13] += acc;                                    \
    acc -= E64;          ring[(OFF) + 14] += acc;                                    \
    acc -= O73;          ring[(OFF) + 15] += acc;                                    \
    acc -= E64;          ring[(OFF) + 16] += acc;                                    \
    acc -= O75;          ring[(OFF) + 17] += acc;                                    \
    acc -= E64;          ring[(OFF) + 18] += acc;                                    \
    acc -= O75;          ring[(OFF) + 19] += acc;                                    \
                         ring[(OFF) + 20] += acc;                                    \
    acc -= O75;          ring[(OFF) + 21] += acc;                                    \
  }

// R4/R6-proven single-t spike accumulation (two u64 streams), result in CV.
// NOTE (R5/R7): widening to 4 streams or fusing two t's loops LOWERS VGPR packing
// (32->28) and VALUBusy (73->65%) -> ~10% regression. Keep exactly 2 streams.
#define SPIKES(LI, CV)                                                               \
  {                                                                                  \
    const int cnt = __builtin_amdgcn_readfirstlane(min(s_cnt[(LI)], LISTCAP));       \
    const unsigned short* lp = &s_list[(LI)][0];                                     \
    unsigned long long ca = 0, cb = 0;                                               \
    int i = 0;                                                                       \
    for (; i + 1 < cnt; i += 2) {                                                    \
      ca += 1ull << wt8[((unsigned)lp[i] << 10) + tid];                              \
      cb += 1ull << wt8[((unsigned)lp[i + 1] << 10) + tid];                          \
    }                                                                                \
    if (i < cnt) ca += 1ull << wt8[((unsigned)lp[i] << 10) + tid];                   \
    CV = ca + cb;                                                                    \
  }

// emit for one t: head-partial store (j<KS) or wave butterfly argmax (wave-uniform j)
#define EMIT(RV, JJ)                                                                 \
  {                                                                                  \
    if ((JJ) < KS) {                                                                 \
      hb[(size_t)(JJ) * 1024] = (unsigned short)(RV);                                \
    } else {                                                                         \
      unsigned key = ((unsigned)(RV) << 10) | invn;                                  \
      _Pragma("unroll")                                                              \
      for (int off = 32; off > 0; off >>= 1) {                                       \
        unsigned o = __shfl_xor(key, off, 64);                                       \
        key = key > o ? key : o;                                                     \
      }                                                                              \
      if ((tid & 63) == 0) atomicMax(&smax[(JJ) - KS], key);                         \
    }                                                                                \
  }

// ---- K3a (split path): halo-free chunk. R4's spike loop; t-loop unrolled x2 with
//      static ring rotation (ring[23], one shift-by-2 per pair).
__global__ void __launch_bounds__(1024, 8)
k_mainA(const unsigned char* __restrict__ wt8,
        const unsigned long long* __restrict__ bm,
        unsigned* __restrict__ red,
        unsigned short* __restrict__ headb,
        unsigned short* __restrict__ tailb) {
  __shared__ unsigned short s_list[CH][LISTCAP];
  __shared__ int s_cnt[CH];
  __shared__ unsigned smax[CH - KS];

  const int tid = threadIdx.x;
  const int b = blockIdx.y;
  const int ck = blockIdx.x;
  const int lo = ck * CH;
  const int hi = min(TP - 1, lo + CH - 1);
  const int nt_in = min(hi, T_DIM - 1) - lo + 1;
  const int n_full = hi - lo - (KS - 1);   // t in [lo+21, hi]

  for (int i = tid; i < nt_in; i += 1024) s_cnt[i] = 0;
  for (int i = tid; i < n_full; i += 1024) smax[i] = 0u;
  __syncthreads();

  const unsigned long long* bmb = bm + ((size_t)b * 512 + lo) * BMSTRIDE;
  const int ntask = nt_in * SW64;
  for (int task = tid; task < ntask; task += 1024) {
    const int li = task / SW64;
    const int sw = task - li * SW64;
    unsigned long long w = bmb[(size_t)li * BMSTRIDE + sw];
    if (w) {
      int cc = __popcll(w);
      int pos = atomicAdd(&s_cnt[li], cc);
      const int sb = sw * 64;
      while (w) {
        int j = __builtin_ctzll(w);
        if (pos < LISTCAP) s_list[li][pos] = (unsigned short)(sb + j);
        ++pos;
        w &= (w - 1);
      }
    }
  }
  __syncthreads();

  int ring[KS + 2];                         // 23-deep: step-B chain reaches ring[22]
  #pragma unroll
  for (int i = 0; i <= KS + 1; ++i) ring[i] = 0;

  const unsigned invn = (unsigned)(1023 - tid);
  unsigned short* hb = headb + ((size_t)b * NCHUNK + ck) * (KS * 1024) + tid;

  // all chunks have an even t-count (66 or 60) and T_DIM-lo is even -> pairs aligned
  for (int t = lo; t <= hi; t += 2) {
    const int j = t - lo;

    // --- step A (t): emit then accumulate t's spikes at ring offset 0
    EMIT(ring[0], j)
    if (t < T_DIM) {
      unsigned long long cA;
      SPIKES(j, cA)
      CHAIN(cA, 0)
    }

    // --- step B (t+1): ring[1] now includes t's tau=1 contribution
    EMIT(ring[1], j + 1)
    if (t + 1 < T_DIM) {
      unsigned long long cB;
      SPIKES(j + 1, cB)
      CHAIN(cB, 1)
    }

    // one shift-by-2 per pair (21 moves + 2 zeros, vs 2x22 single shifts)
    #pragma unroll
    for (int q = 0; q <= KS - 1; ++q) ring[q] = ring[q + 2];
    ring[KS] = 0;
    ring[KS + 1] = 0;
  }

  // tail: ring[0..20] = own-spike contributions to t = hi+1 .. hi+21
  if (ck < NCHUNK - 1) {
    unsigned short* tb = tailb + ((size_t)b * NCHUNK + ck) * (KS * 1024) + tid;
    #pragma unroll
    for (int j2 = 0; j2 < KS; ++j2) tb[(size_t)j2 * 1024] = (unsigned short)ring[j2];
  }

  __syncthreads();
  for (int i = tid; i < n_full; i += 1024)
    red[(unsigned)b * TP + (unsigned)(lo + KS + i)] = smax[i];
}

// ---- K3b (split path): head fixup. full(lo+j) = head_partial + prev_tail; argmax.
__global__ void __launch_bounds__(1024)
k_fix(const unsigned short* __restrict__ headb,
      const unsigned short* __restrict__ tailb,
      unsigned* __restrict__ red) {
  __shared__ unsigned smax[KS];
  const int tid = threadIdx.x;
  const int b = blockIdx.y, ck = blockIdx.x;
  const int lo = ck * CH;
  if (tid < KS) smax[tid] = 0u;
  __syncthreads();
  const size_t base = ((size_t)b * NCHUNK + ck) * (KS * 1024) + tid;
  const unsigned invn = (unsigned)(1023 - tid);
  for (int j = 0; j < KS; ++j) {
    int v = headb[base + (size_t)j * 1024];
    if (ck > 0) v += tailb[base - (size_t)KS * 1024 + (size_t)j * 1024];
    unsigned key = ((unsigned)v << 10) | invn;
    #pragma unroll
    for (int off = 32; off > 0; off >>= 1) {
      unsigned o = __shfl_xor(key, off, 64);
      key = key > o ? key : o;
    }
    if ((tid & 63) == 0) atomicMax(&smax[j], key);
  }
  __syncthreads();
  if (tid < KS) red[(unsigned)b * TP + (unsigned)(lo + tid)] = smax[tid];
}

// ---- K3 (fallback path, ws_size too small): halo kernel, single-t body
__global__ void __launch_bounds__(1024, 8)
k_mainH(const unsigned char* __restrict__ wt8,
        const unsigned long long* __restrict__ bm,
        unsigned* __restrict__ red) {
  __shared__ unsigned short s_list[87][LISTCAP];
  __shared__ int s_cnt[87];
  __shared__ unsigned smax[CH];

  const int tid = threadIdx.x;
  const int b = blockIdx.y;
  const int lo = blockIdx.x * CH;
  const int hi = min(TP - 1, lo + CH - 1);
  const int t0 = max(0, lo - KS);
  const int n_emit = hi - lo + 1;
  const int nt_in = min(hi, T_DIM - 1) - t0 + 1;

  for (int i = tid; i < nt_in; i += 1024) s_cnt[i] = 0;
  for (int i = tid; i < n_emit; i += 1024) smax[i] = 0u;
  __syncthreads();

  const unsigned long long* bmb = bm + ((size_t)b * 512 + t0) * BMSTRIDE;
  const int ntask = nt_in * SW64;
  for (int task = tid; task < ntask; task += 1024) {
    const int li = task / SW64;
    const int sw = task - li * SW64;
    unsigned long long w = bmb[(size_t)li * BMSTRIDE + sw];
    if (w) {
      int cc = __popcll(w);
      int pos = atomicAdd(&s_cnt[li], cc);
      const int sb = sw * 64;
      while (w) {
        int j = __builtin_ctzll(w);
        if (pos < LISTCAP) s_list[li][pos] = (unsigned short)(sb + j);
        ++pos;
        w &= (w - 1);
      }
    }
  }
  __syncthreads();

  int ring[KS + 2];
  #pragma unroll
  for (int i = 0; i <= KS + 1; ++i) ring[i] = 0;

  const unsigned invn = (unsigned)(1023 - tid);

  for (int t = t0; t <= hi; ++t) {
    if (t >= lo) {
      unsigned key = ((unsigned)ring[0] << 10) | invn;
      #pragma unroll
      for (int off = 32; off > 0; off >>= 1) {
        unsigned o = __shfl_xor(key, off, 64);
        key = key > o ? key : o;
      }
      if ((tid & 63) == 0) atomicMax(&smax[t - lo], key);
    }
    if (t < T_DIM) {
      const int li = t - t0;
      unsigned long long c;
      SPIKES(li, c)
      CHAIN(c, 0)
    }
    #pragma unroll
    for (int q = 0; q < KS + 1; ++q) ring[q] = ring[q + 1];
    ring[KS + 1] = 0;
  }

  __syncthreads();
  for (int i = tid; i < n_emit; i += 1024)
    red[(unsigned)b * TP + (unsigned)(lo + i)] = smax[i];
}

// ---- K4: winner-take-all dep scan, one wave per batch row
__global__ void __launch_bounds__(256)
k_scan(const unsigned* __restrict__ red, unsigned* __restrict__ winner) {
  const int wv = (int)((blockIdx.x * 256 + threadIdx.x) >> 6);
  const int lane = threadIdx.x & 63;
  if (wv >= B_DIM) return;
  const unsigned* r = red + wv * TP;
  unsigned* wn = winner + wv * TP;
  int dep = 0;
  for (int base = 0; base < TP; base += 64) {
    const int nt = min(64, TP - base);
    unsigned key = (lane < nt) ? r[base + lane] : 0u;
    unsigned w = 0;
    for (int j = 0; j < nt; ++j) {
      unsigned kj = __shfl(key, j, 64);
      bool cond = ((int)(kj >> 10) > THETA) && (dep == 0);
      if (cond && lane == j) w = 1024u - (kj & 1023u);
      dep += cond ? 22 : 0;
      dep = max(0, dep - 1);
    }
    if (lane < nt) wn[base + lane] = w;
  }
}

// ---- K5: fused zero+scatter output fill (writes all 137 MB exactly once)
__global__ void __launch_bounds__(256)
k_fill(const unsigned* __restrict__ winner, int* __restrict__ out) {
  const int n = blockIdx.x;
  const int b = blockIdx.y;
  const unsigned* wn = winner + b * TP;
  int* o = out + ((size_t)b * N_DIM + n) * TP;
  const unsigned target = (unsigned)(n + 1);
  int2* o2 = (int2*)o;
  for (int i = threadIdx.x; i < TP / 2; i += 256) {
    int2 v;
    v.x = (wn[2 * i]     == target) ? 1 : 0;
    v.y = (wn[2 * i + 1] == target) ? 1 : 0;
    o2[i] = v;
  }
}

extern "C" void kernel_launch(void* const* d_in, const int* in_sizes, int n_in,
                              void* d_out, int out_size, void* d_ws, size_t ws_size,
                              hipStream_t stream) {
  const float* x = (const float*)d_in[0];
  const int* wgt = (const int*)d_in[1];
  int* out = (int*)d_out;

  // workspace layout
  const size_t OFF_BM   = 802816;                 // wt8: 802,816 B
  const size_t OFF_RED  = OFF_BM + 4194304;       // bm:  4,194,304 B
  const size_t OFF_WIN  = OFF_RED + 133632;       // red: 133,632 B
  const size_t OFF_HEAD = OFF_WIN + 133632;       // winner: 133,632 B
  const size_t HT_SZ    = (size_t)B_DIM * NCHUNK * KS * 1024 * 2;  // 22,020,096 B
  const size_t OFF_TAIL = OFF_HEAD + HT_SZ;
  const size_t NEED_SPLIT = OFF_TAIL + HT_SZ;     // ~49.3 MB

  unsigned char* wt8      = (unsigned char*)d_ws;
  unsigned long long* bm  = (unsigned long long*)((char*)d_ws + OFF_BM);
  unsigned* red           = (unsigned*)((char*)d_ws + OFF_RED);
  unsigned* winner        = (unsigned*)((char*)d_ws + OFF_WIN);

  k_prep<<<3136, 256, 0, stream>>>(wgt, wt8);
  k_bitmap<<<dim3(8, B_DIM), 1024, 0, stream>>>(x, bm);

  if (ws_size >= NEED_SPLIT) {
    unsigned short* headb = (unsigned short*)((char*)d_ws + OFF_HEAD);
    unsigned short* tailb = (unsigned short*)((char*)d_ws + OFF_TAIL);
    k_mainA<<<dim3(NCHUNK, B_DIM), 1024, 0, stream>>>(wt8, bm, red, headb, tailb);
    k_fix<<<dim3(NCHUNK, B_DIM), 1024, 0, stream>>>(headb, tailb, red);
  } else {
    k_mainH<<<dim3(NCHUNK, B_DIM), 1024, 0, stream>>>(wt8, bm, red);
  }

  k_scan<<<(B_DIM * 64 + 255) / 256, 256, 0, stream>>>(red, winner);
  k_fill<<<dim3(N_DIM, B_DIM), 256, 0, stream>>>(winner, out);
}